// Round 8
// baseline (299.456 us; speedup 1.0000x reference)
//
#include <hip/hip_runtime.h>

// PhaseMultiHeadAttention: B=8, N=1024, D=512, H=8, dh=64
// R8 = R7 + m-range split across blocks (grid 2048 -> 4 waves/SIMD at the
// measured 104 VGPR) + bf16 partial-O dump in coalesced fragment chunks +
// separate merge kernel (adds halves, phase/l, LDS transpose, Ob write).
// rel[n,m] = Q[n] . E_rel[m-n+N-1]

typedef __bf16 bf16x8 __attribute__((ext_vector_type(8)));
typedef __bf16 bf16x4 __attribute__((ext_vector_type(4)));
typedef float  f32x4  __attribute__((ext_vector_type(4)));
typedef float  f32x16 __attribute__((ext_vector_type(16)));

#if __has_builtin(__builtin_amdgcn_exp2f)
#define EXP2(x) __builtin_amdgcn_exp2f(x)
#else
#define EXP2(x) exp2f(x)
#endif

#define QSCALE 0.18033688011f   // (1/8) * log2(e), folded into Q at projection

// async global->LDS, 16B per lane; LDS dest = wave-uniform base + lane*16
#define GLOAD_LDS16(g, l)                                                      \
    __builtin_amdgcn_global_load_lds(                                          \
        (const __attribute__((address_space(1))) unsigned int*)(g),            \
        (__attribute__((address_space(3))) unsigned int*)(l), 16, 0, 0)

// Fragment-stream layouts (per bh, 65536 elems = 128KB):
//  Kf: [t32 = n>>5][ks = d>>4][lane = ((d>>3)&1)*32 + (n&31)][j = d&7]
//  Vf: [t64 = n>>6][ks = (n>>4)&3][dhalf = d>>5][lane = ((n>>3)&1)*32 + (d&31)][j = n&7]
//  Ef: like Kf over 2048 rows (l = row index): [t32 = l>>5][ks][lane][j]
// Partial-O chunk layout: [mhalf][slot = bh*32+ntile*2+w][rq 0..7][lane][4]  (bf16)

// ---------------- fused fp32 -> bf16 conversion ----------------
__global__ __launch_bounds__(256) void cvt_all(const float* __restrict__ x,
                                               const float* __restrict__ E,
                                               const float* __restrict__ wq,
                                               const float* __restrict__ wk,
                                               const float* __restrict__ wv,
                                               const float* __restrict__ wo,
                                               __bf16* __restrict__ xb,
                                               __bf16* __restrict__ Ef,
                                               __bf16* __restrict__ wqkv,
                                               __bf16* __restrict__ wob) {
    int i = blockIdx.x * 256 + threadIdx.x;
    if (i >= 1081328 ? i < 1343472 : i < 1048576) {
        const float* s; __bf16* d; int off;
        if      (i < 1048576) { s = x;  d = xb;            off = i; }
        else if (i < 1146864) { s = wq; d = wqkv;          off = i - 1081328; }
        else if (i < 1212400) { s = wk; d = wqkv + 262144; off = i - 1146864; }
        else if (i < 1277936) { s = wv; d = wqkv + 524288; off = i - 1212400; }
        else                  { s = wo; d = wob;           off = i - 1277936; }
        float4 v = *(const float4*)(s + (size_t)off * 4);
        bf16x4 o;
        o[0] = (__bf16)v.x; o[1] = (__bf16)v.y; o[2] = (__bf16)v.z; o[3] = (__bf16)v.w;
        *(bf16x4*)(d + (size_t)off * 4) = o;
    } else if (i >= 1048576 && i < 1081328) {
        // E -> fragment stream
        int off = i - 1048576;
        float4 v = *(const float4*)(E + (size_t)off * 4);
        int e0i = off * 4;
        int l = e0i >> 6, d0 = e0i & 63;
        int t32 = l >> 5, cq = l & 31, ks = d0 >> 4, hf = (d0 >> 3) & 1, j = d0 & 7;
        bf16x4 o;
        o[0] = (__bf16)v.x; o[1] = (__bf16)v.y; o[2] = (__bf16)v.z; o[3] = (__bf16)v.w;
        *(bf16x4*)(Ef + ((size_t)((t32 * 4 + ks) * 64) + hf * 32 + cq) * 8 + j) = o;
    }
}

// ---------------- QKV projection GEMM ----------------
__global__ __launch_bounds__(256) void gemm_qkv(const __bf16* __restrict__ X,
                                                const __bf16* __restrict__ W,
                                                __bf16* __restrict__ Qb,
                                                __bf16* __restrict__ Kf,
                                                __bf16* __restrict__ Vf) {
    __shared__ __bf16 Xs[128][64];
    __shared__ __bf16 Ws[128][64];
    const int tid = threadIdx.x;
    const int wave = tid >> 6, lane = tid & 63;
    const int col = lane & 15, quad = lane >> 4;
    const int m_base = blockIdx.x * 128;
    const int j_base = blockIdx.y * 128;
    const bool qk = (j_base < 1024);
    const int wm = (wave & 1) * 64;
    const int wn = (wave >> 1) * 64;
    const f32x4 fz = {0.f, 0.f, 0.f, 0.f};
    f32x4 acc[4][4];
#pragma unroll
    for (int i = 0; i < 4; ++i)
#pragma unroll
        for (int j = 0; j < 4; ++j) acc[i][j] = fz;

    for (int k0 = 0; k0 < 512; k0 += 64) {
#pragma unroll
        for (int p = 0; p < 4; ++p) {
            int s = tid + p * 256;
            int row = s >> 3, cc = (s & 7) * 8;
            GLOAD_LDS16(X + (size_t)(m_base + row) * 512 + k0 + cc, &Xs[0][0] + (size_t)s * 8);
            GLOAD_LDS16(W + (size_t)(j_base + row) * 512 + k0 + cc, &Ws[0][0] + (size_t)s * 8);
        }
        __syncthreads();
#pragma unroll
        for (int kk = 0; kk < 64; kk += 32) {
            bf16x8 xa[4], wb[4];
#pragma unroll
            for (int i = 0; i < 4; ++i) xa[i] = *(const bf16x8*)(&Xs[wm + i * 16 + col][kk + quad * 8]);
#pragma unroll
            for (int j = 0; j < 4; ++j) wb[j] = *(const bf16x8*)(&Ws[wn + j * 16 + col][kk + quad * 8]);
            if (qk) {
#pragma unroll
                for (int i = 0; i < 4; ++i)
#pragma unroll
                    for (int j = 0; j < 4; ++j)
                        acc[i][j] = __builtin_amdgcn_mfma_f32_16x16x32_bf16(wb[i], xa[j], acc[i][j], 0, 0, 0);
            } else {
#pragma unroll
                for (int i = 0; i < 4; ++i)
#pragma unroll
                    for (int j = 0; j < 4; ++j)
                        acc[i][j] = __builtin_amdgcn_mfma_f32_16x16x32_bf16(xa[i], wb[j], acc[i][j], 0, 0, 0);
            }
        }
        __syncthreads();
    }
    if (qk) {
#pragma unroll
        for (int i = 0; i < 4; ++i) {
#pragma unroll
            for (int j = 0; j < 4; ++j) {
                int jabs = j_base + wn + i * 16 + quad * 4;
                int m = m_base + wm + j * 16 + col;
                int b_ = m >> 10, n = m & 1023;
                int rem = jabs & 511, h = rem >> 6, d = rem & 63;
                bf16x4 v;
                if (jabs < 512) {
                    v[0] = (__bf16)(acc[i][j][0] * QSCALE);
                    v[1] = (__bf16)(acc[i][j][1] * QSCALE);
                    v[2] = (__bf16)(acc[i][j][2] * QSCALE);
                    v[3] = (__bf16)(acc[i][j][3] * QSCALE);
                    *(bf16x4*)(Qb + (((size_t)b_ * 8 + h) * 1024 + n) * 64 + d) = v;
                } else {
                    v[0] = (__bf16)acc[i][j][0]; v[1] = (__bf16)acc[i][j][1];
                    v[2] = (__bf16)acc[i][j][2]; v[3] = (__bf16)acc[i][j][3];
                    int t32 = n >> 5, cq = n & 31, ks = d >> 4, hf = (d >> 3) & 1, jj = d & 7;
                    *(bf16x4*)(Kf + (size_t)(b_ * 8 + h) * 65536 +
                               ((size_t)((t32 * 4 + ks) * 64) + hf * 32 + cq) * 8 + jj) = v;
                }
            }
        }
    } else {
#pragma unroll
        for (int i = 0; i < 4; ++i) {
#pragma unroll
            for (int j = 0; j < 4; ++j) {
                int m = m_base + wm + i * 16 + quad * 4;
                int b_ = m >> 10, n = m & 1023;
                int jabs = j_base + wn + j * 16 + col;
                int rem = jabs & 511, h = rem >> 6, d = rem & 63;
                int t64 = n >> 6, ks = (n >> 4) & 3, hf = (n >> 3) & 1, jj = n & 7;
                int dhalf = d >> 5, cq = d & 31;
                bf16x4 v;
                v[0] = (__bf16)acc[i][j][0]; v[1] = (__bf16)acc[i][j][1];
                v[2] = (__bf16)acc[i][j][2]; v[3] = (__bf16)acc[i][j][3];
                *(bf16x4*)(Vf + (size_t)(b_ * 8 + h) * 65536 +
                           ((size_t)(((t64 * 4 + ks) * 2 + dhalf) * 64) + hf * 32 + cq) * 8 + jj) = v;
            }
        }
    }
}

// ---------------- flash attention, m-split across blocks ----------------
// grid 2048 flat: bh = bid&63 (XCD = bh%8), rest = bid>>6: ntile = rest&15,
// mhalf = rest>>4. Each block: 64 Q-rows (2 waves x 32), 8 m-tiles of 64.
__global__ __launch_bounds__(128, 4) void flash_kernel(const __bf16* __restrict__ Qb,
                                                       const __bf16* __restrict__ Kf,
                                                       const __bf16* __restrict__ Vf,
                                                       const __bf16* __restrict__ Ef,
                                                       __bf16* __restrict__ Opart,
                                                       float* __restrict__ Lpart) {
    const int bid = blockIdx.x;
    const int bh = bid & 63;
    const int rest = bid >> 6;
    const int ntile = rest & 15;
    const int mhalf = rest >> 4;
    const int w = threadIdx.x >> 6, lane = threadIdx.x & 63;
    const int colq = lane & 31, half = lane >> 5;
    const int nbase = ntile * 64 + w * 32;

    __shared__ __bf16 Pw[2][32][72];   // per-wave P staging; conflict-free

    f32x16 z16;
#pragma unroll
    for (int i = 0; i < 16; ++i) z16[i] = 0.f;

    bf16x8 a_q[4];
#pragma unroll
    for (int ks = 0; ks < 4; ++ks)
        a_q[ks] = *(const bf16x8*)(Qb + ((size_t)bh * 1024 + nbase + colq) * 64 + ks * 16 + half * 8);

    f32x16 o0 = z16, o1 = z16;
    float rowsum[16];
#pragma unroll
    for (int i = 0; i < 16; ++i) rowsum[i] = 0.f;

    const __bf16* Kfb = Kf + (size_t)bh * 65536;
    const __bf16* Vfb = Vf + (size_t)bh * 65536;

#pragma unroll 2
    for (int t = 0; t < 8; ++t) {
        const int m0 = mhalf * 512 + t * 64;
        const int t32 = m0 >> 5;
        const int te = (m0 - nbase + 992) >> 5;   // E window 32-tile (always >= 0)
        f32x16 qe0 = z16, qe1 = z16, qe2 = z16, s0 = z16, s1 = z16;
#pragma unroll
        for (int ks = 0; ks < 4; ++ks) {
            bf16x8 e0 = *(const bf16x8*)(Ef + ((size_t)((te * 4 + ks) * 64) + lane) * 8);
            bf16x8 e1 = *(const bf16x8*)(Ef + ((size_t)(((te + 1) * 4 + ks) * 64) + lane) * 8);
            bf16x8 e2 = *(const bf16x8*)(Ef + ((size_t)(((te + 2) * 4 + ks) * 64) + lane) * 8);
            bf16x8 k0 = *(const bf16x8*)(Kfb + ((size_t)((t32 * 4 + ks) * 64) + lane) * 8);
            bf16x8 k1 = *(const bf16x8*)(Kfb + ((size_t)(((t32 + 1) * 4 + ks) * 64) + lane) * 8);
            qe0 = __builtin_amdgcn_mfma_f32_32x32x16_bf16(a_q[ks], e0, qe0, 0, 0, 0);
            qe1 = __builtin_amdgcn_mfma_f32_32x32x16_bf16(a_q[ks], e1, qe1, 0, 0, 0);
            qe2 = __builtin_amdgcn_mfma_f32_32x32x16_bf16(a_q[ks], e2, qe2, 0, 0, 0);
            s0  = __builtin_amdgcn_mfma_f32_32x32x16_bf16(a_q[ks], k0, s0, 0, 0, 0);
            s1  = __builtin_amdgcn_mfma_f32_32x32x16_bf16(a_q[ks], k1, s1, 0, 0, 0);
        }
        // skew (shfl in 32-wide D-layout), exp2, P store (Q pre-scaled)
#pragma unroll
        for (int r = 0; r < 16; ++r) {
            int row = (r & 3) + 8 * (r >> 2) + 4 * half;
            int tt = colq + 31 - row;              // 0..62
            int src = (tt & 31) | (half << 5);
            float sh0 = __shfl(qe0[r], src, 64);
            float sh1 = __shfl(qe1[r], src, 64);
            float sh2 = __shfl(qe2[r], src, 64);
            bool sel = (tt >= 32);
            float rel0 = sel ? sh1 : sh0;
            float rel1 = sel ? sh2 : sh1;
            float p0 = EXP2(s0[r] + rel0);
            float p1 = EXP2(s1[r] + rel1);
            rowsum[r] += p0 + p1;
            Pw[w][row][colq]      = (__bf16)p0;
            Pw[w][row][32 + colq] = (__bf16)p1;
        }
        // O += P @ V (compiler inserts the DS RAW waits; Pw is wave-private)
#pragma unroll
        for (int ks = 0; ks < 4; ++ks) {
            bf16x8 pa = *(const bf16x8*)(&Pw[w][colq][ks * 16 + half * 8]);
            bf16x8 v0 = *(const bf16x8*)(Vfb + ((size_t)((((m0 >> 6) * 4 + ks) * 2 + 0) * 64) + lane) * 8);
            bf16x8 v1 = *(const bf16x8*)(Vfb + ((size_t)((((m0 >> 6) * 4 + ks) * 2 + 1) * 64) + lane) * 8);
            o0 = __builtin_amdgcn_mfma_f32_32x32x16_bf16(pa, v0, o0, 0, 0, 0);
            o1 = __builtin_amdgcn_mfma_f32_32x32x16_bf16(pa, v1, o1, 0, 0, 0);
        }
    }

    // ---- partial epilogue: reduce rowsum over lanes, dump O chunks + L ----
#pragma unroll
    for (int r = 0; r < 16; ++r) {
        float l = rowsum[r];
        l += __shfl_xor(l, 1, 32);
        l += __shfl_xor(l, 2, 32);
        l += __shfl_xor(l, 4, 32);
        l += __shfl_xor(l, 8, 32);
        l += __shfl_xor(l, 16, 32);
        rowsum[r] = l;
    }
    if (colq == 0) {
#pragma unroll
        for (int r = 0; r < 16; ++r) {
            int row = (r & 3) + 8 * (r >> 2) + 4 * half;
            Lpart[(size_t)mhalf * 65536 + (size_t)bh * 1024 + nbase + row] = rowsum[r];
        }
    }
    {
        const int slot = (bh * 16 + ntile) * 2 + w;
        __bf16* ob = Opart + ((size_t)mhalf * 2048 + slot) * 2048;
#pragma unroll
        for (int rq = 0; rq < 4; ++rq) {
            bf16x4 c0, c1;
#pragma unroll
            for (int i = 0; i < 4; ++i) { c0[i] = (__bf16)o0[rq * 4 + i]; c1[i] = (__bf16)o1[rq * 4 + i]; }
            *(bf16x4*)(ob + ((size_t)rq * 64 + lane) * 4)       = c0;
            *(bf16x4*)(ob + ((size_t)(rq + 4) * 64 + lane) * 4) = c1;
        }
    }
}

// ---------------- merge partial O halves, phase/l, transpose, write Ob ----------------
// grid 512 x 256: wave g handles slot g (32 rows x 64 d).
__global__ __launch_bounds__(256) void merge_kernel(const __bf16* __restrict__ Opart,
                                                    const float* __restrict__ Lpart,
                                                    const float* __restrict__ phase,
                                                    __bf16* __restrict__ Ob) {
    const int wv = threadIdx.x >> 6, lane = threadIdx.x & 63;
    const int g = blockIdx.x * 4 + wv;          // slot
    const int w = g & 1, ntile = (g >> 1) & 15, bh = g >> 5;
    const int nbase = ntile * 64 + w * 32;
    const int colq = lane & 31, half = lane >> 5;

    __shared__ __bf16 Pw[4][32][72];

    const __bf16* p0 = Opart + (size_t)g * 2048;
    const __bf16* p1 = Opart + ((size_t)2048 + g) * 2048;
#pragma unroll
    for (int rq = 0; rq < 8; ++rq) {
        bf16x4 a = *(const bf16x4*)(p0 + ((size_t)rq * 64 + lane) * 4);
        bf16x4 b = *(const bf16x4*)(p1 + ((size_t)rq * 64 + lane) * 4);
#pragma unroll
        for (int i = 0; i < 4; ++i) {
            int row = i + 8 * (rq & 3) + 4 * half;
            int n = nbase + row;
            float l = Lpart[(size_t)bh * 1024 + n] + Lpart[65536 + (size_t)bh * 1024 + n];
            float f = phase[(size_t)bh * 1024 + n] / l;
            Pw[wv][row][colq + 32 * (rq >> 2)] = (__bf16)(((float)a[i] + (float)b[i]) * f);
        }
    }
    // wave-private LDS RAW; compiler inserts the wait
    {
        int row = lane >> 1, dseg = lane & 1;
        int b_ = bh >> 3, hh = bh & 7;
        bf16x8 u0 = *(const bf16x8*)(&Pw[wv][row][dseg * 32]);
        bf16x8 u1 = *(const bf16x8*)(&Pw[wv][row][dseg * 32 + 8]);
        bf16x8 u2 = *(const bf16x8*)(&Pw[wv][row][dseg * 32 + 16]);
        bf16x8 u3 = *(const bf16x8*)(&Pw[wv][row][dseg * 32 + 24]);
        size_t obase = ((size_t)b_ * 1024 + nbase + row) * 512 + hh * 64 + dseg * 32;
        *(bf16x8*)(Ob + obase)      = u0;
        *(bf16x8*)(Ob + obase + 8)  = u1;
        *(bf16x8*)(Ob + obase + 16) = u2;
        *(bf16x8*)(Ob + obase + 24) = u3;
    }
}

// ---------------- output projection GEMM ----------------
__global__ __launch_bounds__(256) void gemm_out(const __bf16* __restrict__ X,
                                                const __bf16* __restrict__ W,
                                                const float* __restrict__ bo,
                                                float* __restrict__ out) {
    __shared__ __bf16 Xs[128][64];
    __shared__ __bf16 Ws[128][64];
    const int tid = threadIdx.x;
    const int wave = tid >> 6, lane = tid & 63;
    const int col = lane & 15, quad = lane >> 4;
    const int m_base = blockIdx.x * 128;
    const int j_base = blockIdx.y * 128;
    const int wm = (wave & 1) * 64;
    const int wn = (wave >> 1) * 64;
    const f32x4 fz = {0.f, 0.f, 0.f, 0.f};
    f32x4 acc[4][4];
#pragma unroll
    for (int i = 0; i < 4; ++i)
#pragma unroll
        for (int j = 0; j < 4; ++j) acc[i][j] = fz;

    for (int k0 = 0; k0 < 512; k0 += 64) {
#pragma unroll
        for (int p = 0; p < 4; ++p) {
            int s = tid + p * 256;
            int row = s >> 3, cc = (s & 7) * 8;
            GLOAD_LDS16(X + (size_t)(m_base + row) * 512 + k0 + cc, &Xs[0][0] + (size_t)s * 8);
            GLOAD_LDS16(W + (size_t)(j_base + row) * 512 + k0 + cc, &Ws[0][0] + (size_t)s * 8);
        }
        __syncthreads();
#pragma unroll
        for (int kk = 0; kk < 64; kk += 32) {
            bf16x8 xa[4], wb[4];
#pragma unroll
            for (int i = 0; i < 4; ++i) xa[i] = *(const bf16x8*)(&Xs[wm + i * 16 + col][kk + quad * 8]);
#pragma unroll
            for (int j = 0; j < 4; ++j) wb[j] = *(const bf16x8*)(&Ws[wn + j * 16 + col][kk + quad * 8]);
#pragma unroll
            for (int i = 0; i < 4; ++i)
#pragma unroll
                for (int j = 0; j < 4; ++j)
                    acc[i][j] = __builtin_amdgcn_mfma_f32_16x16x32_bf16(wb[i], xa[j], acc[i][j], 0, 0, 0);
        }
        __syncthreads();
    }
#pragma unroll
    for (int i = 0; i < 4; ++i) {
#pragma unroll
        for (int j = 0; j < 4; ++j) {
            int jabs = j_base + wn + i * 16 + quad * 4;
            int m = m_base + wm + j * 16 + col;
            f32x4 bv = *(const f32x4*)(bo + jabs);
            f32x4 o = acc[i][j] + bv;
            *(f32x4*)(out + (size_t)m * 512 + jabs) = o;
        }
    }
}

extern "C" void kernel_launch(void* const* d_in, const int* in_sizes, int n_in,
                              void* d_out, int out_size, void* d_ws, size_t ws_size,
                              hipStream_t stream) {
    (void)in_sizes; (void)n_in; (void)out_size; (void)ws_size;
    const float* x     = (const float*)d_in[0];
    const float* phase = (const float*)d_in[1];
    const float* E_rel = (const float*)d_in[2];
    const float* W_q   = (const float*)d_in[3];
    const float* W_k   = (const float*)d_in[4];
    const float* W_v   = (const float*)d_in[5];
    const float* W_o   = (const float*)d_in[6];
    const float* b_o   = (const float*)d_in[7];
    float* out = (float*)d_out;

    char* ws = (char*)d_ws;
    __bf16* xb    = (__bf16*)(ws);                 //  8,388,608 B
    __bf16* wqkv  = (__bf16*)(ws + 8388608);       //  1,572,864 B
    __bf16* wob   = (__bf16*)(ws + 9961472);       //    524,288 B
    __bf16* Ef    = (__bf16*)(ws + 10485760);      //    262,144 B fragment stream
    __bf16* Qb    = (__bf16*)(ws + 10747904);      //  8,388,608 B (pre-scaled)
    __bf16* Kf    = (__bf16*)(ws + 19136512);      //  8,388,608 B fragment stream
    __bf16* Vf    = (__bf16*)(ws + 27525120);      //  8,388,608 B fragment stream
    __bf16* Ob    = (__bf16*)(ws + 35913728);      //  8,388,608 B
    __bf16* Opart = (__bf16*)(ws + 44302336);      // 16,777,216 B partial O chunks
    float*  Lpart = (float*)(ws + 61079552);       //    524,288 B partial row-sums
                                                   // total 61,603,840 B

    cvt_all<<<dim3(5249), dim3(256), 0, stream>>>(x, E_rel, W_q, W_k, W_v, W_o,
                                                  xb, Ef, wqkv, wob);
    gemm_qkv<<<dim3(64, 12), dim3(256), 0, stream>>>(xb, wqkv, Qb, Kf, Vf);
    flash_kernel<<<dim3(2048), dim3(128), 0, stream>>>(Qb, Kf, Vf, Ef, Opart, Lpart);
    merge_kernel<<<dim3(512), dim3(256), 0, stream>>>(Opart, Lpart, phase, Ob);
    gemm_out<<<dim3(64, 4), dim3(256), 0, stream>>>(Ob, wob, b_o, out);
}

// Round 9
// 239.112 us; speedup vs baseline: 1.2524x; 1.2524x over previous
//
#include <hip/hip_runtime.h>

// PhaseMultiHeadAttention: B=8, N=1024, D=512, H=8, dh=64
// R9 = R8 with the spill fixed: __launch_bounds__(128) (no min-waves cap).
// R8's forced 4-waves/EU budget (128 regs) spilled ~150 live regs to scratch
// (FETCH 249MB / WRITE 365MB of pure spill traffic). Grid stays 2048 (m-split
// across blocks + merge kernel) so the HW picks 3-4 waves/SIMD naturally.
// rel[n,m] = Q[n] . E_rel[m-n+N-1]

typedef __bf16 bf16x8 __attribute__((ext_vector_type(8)));
typedef __bf16 bf16x4 __attribute__((ext_vector_type(4)));
typedef float  f32x4  __attribute__((ext_vector_type(4)));
typedef float  f32x16 __attribute__((ext_vector_type(16)));

#if __has_builtin(__builtin_amdgcn_exp2f)
#define EXP2(x) __builtin_amdgcn_exp2f(x)
#else
#define EXP2(x) exp2f(x)
#endif

#define QSCALE 0.18033688011f   // (1/8) * log2(e), folded into Q at projection

// async global->LDS, 16B per lane; LDS dest = wave-uniform base + lane*16
#define GLOAD_LDS16(g, l)                                                      \
    __builtin_amdgcn_global_load_lds(                                          \
        (const __attribute__((address_space(1))) unsigned int*)(g),            \
        (__attribute__((address_space(3))) unsigned int*)(l), 16, 0, 0)

// Fragment-stream layouts (per bh, 65536 elems = 128KB):
//  Kf: [t32 = n>>5][ks = d>>4][lane = ((d>>3)&1)*32 + (n&31)][j = d&7]
//  Vf: [t64 = n>>6][ks = (n>>4)&3][dhalf = d>>5][lane = ((n>>3)&1)*32 + (d&31)][j = n&7]
//  Ef: like Kf over 2048 rows (l = row index): [t32 = l>>5][ks][lane][j]
// Partial-O chunk layout: [mhalf][slot = bh*32+ntile*2+w][rq 0..7][lane][4]  (bf16)

// ---------------- fused fp32 -> bf16 conversion ----------------
__global__ __launch_bounds__(256) void cvt_all(const float* __restrict__ x,
                                               const float* __restrict__ E,
                                               const float* __restrict__ wq,
                                               const float* __restrict__ wk,
                                               const float* __restrict__ wv,
                                               const float* __restrict__ wo,
                                               __bf16* __restrict__ xb,
                                               __bf16* __restrict__ Ef,
                                               __bf16* __restrict__ wqkv,
                                               __bf16* __restrict__ wob) {
    int i = blockIdx.x * 256 + threadIdx.x;
    if (i >= 1081328 ? i < 1343472 : i < 1048576) {
        const float* s; __bf16* d; int off;
        if      (i < 1048576) { s = x;  d = xb;            off = i; }
        else if (i < 1146864) { s = wq; d = wqkv;          off = i - 1081328; }
        else if (i < 1212400) { s = wk; d = wqkv + 262144; off = i - 1146864; }
        else if (i < 1277936) { s = wv; d = wqkv + 524288; off = i - 1212400; }
        else                  { s = wo; d = wob;           off = i - 1277936; }
        float4 v = *(const float4*)(s + (size_t)off * 4);
        bf16x4 o;
        o[0] = (__bf16)v.x; o[1] = (__bf16)v.y; o[2] = (__bf16)v.z; o[3] = (__bf16)v.w;
        *(bf16x4*)(d + (size_t)off * 4) = o;
    } else if (i >= 1048576 && i < 1081328) {
        // E -> fragment stream
        int off = i - 1048576;
        float4 v = *(const float4*)(E + (size_t)off * 4);
        int e0i = off * 4;
        int l = e0i >> 6, d0 = e0i & 63;
        int t32 = l >> 5, cq = l & 31, ks = d0 >> 4, hf = (d0 >> 3) & 1, j = d0 & 7;
        bf16x4 o;
        o[0] = (__bf16)v.x; o[1] = (__bf16)v.y; o[2] = (__bf16)v.z; o[3] = (__bf16)v.w;
        *(bf16x4*)(Ef + ((size_t)((t32 * 4 + ks) * 64) + hf * 32 + cq) * 8 + j) = o;
    }
}

// ---------------- QKV projection GEMM ----------------
__global__ __launch_bounds__(256) void gemm_qkv(const __bf16* __restrict__ X,
                                                const __bf16* __restrict__ W,
                                                __bf16* __restrict__ Qb,
                                                __bf16* __restrict__ Kf,
                                                __bf16* __restrict__ Vf) {
    __shared__ __bf16 Xs[128][64];
    __shared__ __bf16 Ws[128][64];
    const int tid = threadIdx.x;
    const int wave = tid >> 6, lane = tid & 63;
    const int col = lane & 15, quad = lane >> 4;
    const int m_base = blockIdx.x * 128;
    const int j_base = blockIdx.y * 128;
    const bool qk = (j_base < 1024);
    const int wm = (wave & 1) * 64;
    const int wn = (wave >> 1) * 64;
    const f32x4 fz = {0.f, 0.f, 0.f, 0.f};
    f32x4 acc[4][4];
#pragma unroll
    for (int i = 0; i < 4; ++i)
#pragma unroll
        for (int j = 0; j < 4; ++j) acc[i][j] = fz;

    for (int k0 = 0; k0 < 512; k0 += 64) {
#pragma unroll
        for (int p = 0; p < 4; ++p) {
            int s = tid + p * 256;
            int row = s >> 3, cc = (s & 7) * 8;
            GLOAD_LDS16(X + (size_t)(m_base + row) * 512 + k0 + cc, &Xs[0][0] + (size_t)s * 8);
            GLOAD_LDS16(W + (size_t)(j_base + row) * 512 + k0 + cc, &Ws[0][0] + (size_t)s * 8);
        }
        __syncthreads();
#pragma unroll
        for (int kk = 0; kk < 64; kk += 32) {
            bf16x8 xa[4], wb[4];
#pragma unroll
            for (int i = 0; i < 4; ++i) xa[i] = *(const bf16x8*)(&Xs[wm + i * 16 + col][kk + quad * 8]);
#pragma unroll
            for (int j = 0; j < 4; ++j) wb[j] = *(const bf16x8*)(&Ws[wn + j * 16 + col][kk + quad * 8]);
            if (qk) {
#pragma unroll
                for (int i = 0; i < 4; ++i)
#pragma unroll
                    for (int j = 0; j < 4; ++j)
                        acc[i][j] = __builtin_amdgcn_mfma_f32_16x16x32_bf16(wb[i], xa[j], acc[i][j], 0, 0, 0);
            } else {
#pragma unroll
                for (int i = 0; i < 4; ++i)
#pragma unroll
                    for (int j = 0; j < 4; ++j)
                        acc[i][j] = __builtin_amdgcn_mfma_f32_16x16x32_bf16(xa[i], wb[j], acc[i][j], 0, 0, 0);
            }
        }
        __syncthreads();
    }
    if (qk) {
#pragma unroll
        for (int i = 0; i < 4; ++i) {
#pragma unroll
            for (int j = 0; j < 4; ++j) {
                int jabs = j_base + wn + i * 16 + quad * 4;
                int m = m_base + wm + j * 16 + col;
                int b_ = m >> 10, n = m & 1023;
                int rem = jabs & 511, h = rem >> 6, d = rem & 63;
                bf16x4 v;
                if (jabs < 512) {
                    v[0] = (__bf16)(acc[i][j][0] * QSCALE);
                    v[1] = (__bf16)(acc[i][j][1] * QSCALE);
                    v[2] = (__bf16)(acc[i][j][2] * QSCALE);
                    v[3] = (__bf16)(acc[i][j][3] * QSCALE);
                    *(bf16x4*)(Qb + (((size_t)b_ * 8 + h) * 1024 + n) * 64 + d) = v;
                } else {
                    v[0] = (__bf16)acc[i][j][0]; v[1] = (__bf16)acc[i][j][1];
                    v[2] = (__bf16)acc[i][j][2]; v[3] = (__bf16)acc[i][j][3];
                    int t32 = n >> 5, cq = n & 31, ks = d >> 4, hf = (d >> 3) & 1, jj = d & 7;
                    *(bf16x4*)(Kf + (size_t)(b_ * 8 + h) * 65536 +
                               ((size_t)((t32 * 4 + ks) * 64) + hf * 32 + cq) * 8 + jj) = v;
                }
            }
        }
    } else {
#pragma unroll
        for (int i = 0; i < 4; ++i) {
#pragma unroll
            for (int j = 0; j < 4; ++j) {
                int m = m_base + wm + i * 16 + quad * 4;
                int b_ = m >> 10, n = m & 1023;
                int jabs = j_base + wn + j * 16 + col;
                int rem = jabs & 511, h = rem >> 6, d = rem & 63;
                int t64 = n >> 6, ks = (n >> 4) & 3, hf = (n >> 3) & 1, jj = n & 7;
                int dhalf = d >> 5, cq = d & 31;
                bf16x4 v;
                v[0] = (__bf16)acc[i][j][0]; v[1] = (__bf16)acc[i][j][1];
                v[2] = (__bf16)acc[i][j][2]; v[3] = (__bf16)acc[i][j][3];
                *(bf16x4*)(Vf + (size_t)(b_ * 8 + h) * 65536 +
                           ((size_t)(((t64 * 4 + ks) * 2 + dhalf) * 64) + hf * 32 + cq) * 8 + jj) = v;
            }
        }
    }
}

// ---------------- flash attention, m-split across blocks ----------------
// grid 2048 flat: bh = bid&63 (XCD = bh%8), rest = bid>>6: ntile = rest&15,
// mhalf = rest>>4. Each block: 64 Q-rows (2 waves x 32), 8 m-tiles of 64.
// NO min-waves cap: natural ~104-VGPR allocation, no spill (R8 lesson).
__global__ __launch_bounds__(128) void flash_kernel(const __bf16* __restrict__ Qb,
                                                    const __bf16* __restrict__ Kf,
                                                    const __bf16* __restrict__ Vf,
                                                    const __bf16* __restrict__ Ef,
                                                    __bf16* __restrict__ Opart,
                                                    float* __restrict__ Lpart) {
    const int bid = blockIdx.x;
    const int bh = bid & 63;
    const int rest = bid >> 6;
    const int ntile = rest & 15;
    const int mhalf = rest >> 4;
    const int w = threadIdx.x >> 6, lane = threadIdx.x & 63;
    const int colq = lane & 31, half = lane >> 5;
    const int nbase = ntile * 64 + w * 32;

    __shared__ __bf16 Pw[2][32][72];   // per-wave P staging; conflict-free

    f32x16 z16;
#pragma unroll
    for (int i = 0; i < 16; ++i) z16[i] = 0.f;

    bf16x8 a_q[4];
#pragma unroll
    for (int ks = 0; ks < 4; ++ks)
        a_q[ks] = *(const bf16x8*)(Qb + ((size_t)bh * 1024 + nbase + colq) * 64 + ks * 16 + half * 8);

    f32x16 o0 = z16, o1 = z16;
    float rowsum[16];
#pragma unroll
    for (int i = 0; i < 16; ++i) rowsum[i] = 0.f;

    const __bf16* Kfb = Kf + (size_t)bh * 65536;
    const __bf16* Vfb = Vf + (size_t)bh * 65536;

#pragma unroll 2
    for (int t = 0; t < 8; ++t) {
        const int m0 = mhalf * 512 + t * 64;
        const int t32 = m0 >> 5;
        const int te = (m0 - nbase + 992) >> 5;   // E window 32-tile (always >= 0)
        f32x16 qe0 = z16, qe1 = z16, qe2 = z16, s0 = z16, s1 = z16;
#pragma unroll
        for (int ks = 0; ks < 4; ++ks) {
            bf16x8 e0 = *(const bf16x8*)(Ef + ((size_t)((te * 4 + ks) * 64) + lane) * 8);
            bf16x8 e1 = *(const bf16x8*)(Ef + ((size_t)(((te + 1) * 4 + ks) * 64) + lane) * 8);
            bf16x8 e2 = *(const bf16x8*)(Ef + ((size_t)(((te + 2) * 4 + ks) * 64) + lane) * 8);
            bf16x8 k0 = *(const bf16x8*)(Kfb + ((size_t)((t32 * 4 + ks) * 64) + lane) * 8);
            bf16x8 k1 = *(const bf16x8*)(Kfb + ((size_t)(((t32 + 1) * 4 + ks) * 64) + lane) * 8);
            qe0 = __builtin_amdgcn_mfma_f32_32x32x16_bf16(a_q[ks], e0, qe0, 0, 0, 0);
            qe1 = __builtin_amdgcn_mfma_f32_32x32x16_bf16(a_q[ks], e1, qe1, 0, 0, 0);
            qe2 = __builtin_amdgcn_mfma_f32_32x32x16_bf16(a_q[ks], e2, qe2, 0, 0, 0);
            s0  = __builtin_amdgcn_mfma_f32_32x32x16_bf16(a_q[ks], k0, s0, 0, 0, 0);
            s1  = __builtin_amdgcn_mfma_f32_32x32x16_bf16(a_q[ks], k1, s1, 0, 0, 0);
        }
        // skew (shfl in 32-wide D-layout), exp2, P store (Q pre-scaled)
#pragma unroll
        for (int r = 0; r < 16; ++r) {
            int row = (r & 3) + 8 * (r >> 2) + 4 * half;
            int tt = colq + 31 - row;              // 0..62
            int src = (tt & 31) | (half << 5);
            float sh0 = __shfl(qe0[r], src, 64);
            float sh1 = __shfl(qe1[r], src, 64);
            float sh2 = __shfl(qe2[r], src, 64);
            bool sel = (tt >= 32);
            float rel0 = sel ? sh1 : sh0;
            float rel1 = sel ? sh2 : sh1;
            float p0 = EXP2(s0[r] + rel0);
            float p1 = EXP2(s1[r] + rel1);
            rowsum[r] += p0 + p1;
            Pw[w][row][colq]      = (__bf16)p0;
            Pw[w][row][32 + colq] = (__bf16)p1;
        }
        // O += P @ V (compiler inserts the DS RAW waits; Pw is wave-private)
#pragma unroll
        for (int ks = 0; ks < 4; ++ks) {
            bf16x8 pa = *(const bf16x8*)(&Pw[w][colq][ks * 16 + half * 8]);
            bf16x8 v0 = *(const bf16x8*)(Vfb + ((size_t)((((m0 >> 6) * 4 + ks) * 2 + 0) * 64) + lane) * 8);
            bf16x8 v1 = *(const bf16x8*)(Vfb + ((size_t)((((m0 >> 6) * 4 + ks) * 2 + 1) * 64) + lane) * 8);
            o0 = __builtin_amdgcn_mfma_f32_32x32x16_bf16(pa, v0, o0, 0, 0, 0);
            o1 = __builtin_amdgcn_mfma_f32_32x32x16_bf16(pa, v1, o1, 0, 0, 0);
        }
    }

    // ---- partial epilogue: reduce rowsum over lanes, dump O chunks + L ----
#pragma unroll
    for (int r = 0; r < 16; ++r) {
        float l = rowsum[r];
        l += __shfl_xor(l, 1, 32);
        l += __shfl_xor(l, 2, 32);
        l += __shfl_xor(l, 4, 32);
        l += __shfl_xor(l, 8, 32);
        l += __shfl_xor(l, 16, 32);
        rowsum[r] = l;
    }
    if (colq == 0) {
#pragma unroll
        for (int r = 0; r < 16; ++r) {
            int row = (r & 3) + 8 * (r >> 2) + 4 * half;
            Lpart[(size_t)mhalf * 65536 + (size_t)bh * 1024 + nbase + row] = rowsum[r];
        }
    }
    {
        const int slot = (bh * 16 + ntile) * 2 + w;
        __bf16* ob = Opart + ((size_t)mhalf * 2048 + slot) * 2048;
#pragma unroll
        for (int rq = 0; rq < 4; ++rq) {
            bf16x4 c0, c1;
#pragma unroll
            for (int i = 0; i < 4; ++i) { c0[i] = (__bf16)o0[rq * 4 + i]; c1[i] = (__bf16)o1[rq * 4 + i]; }
            *(bf16x4*)(ob + ((size_t)rq * 64 + lane) * 4)       = c0;
            *(bf16x4*)(ob + ((size_t)(rq + 4) * 64 + lane) * 4) = c1;
        }
    }
}

// ---------------- merge partial O halves, phase/l, transpose, write Ob ----------------
// grid 512 x 256: wave g handles slot g (32 rows x 64 d).
__global__ __launch_bounds__(256) void merge_kernel(const __bf16* __restrict__ Opart,
                                                    const float* __restrict__ Lpart,
                                                    const float* __restrict__ phase,
                                                    __bf16* __restrict__ Ob) {
    const int wv = threadIdx.x >> 6, lane = threadIdx.x & 63;
    const int g = blockIdx.x * 4 + wv;          // slot
    const int w = g & 1, ntile = (g >> 1) & 15, bh = g >> 5;
    const int nbase = ntile * 64 + w * 32;
    const int colq = lane & 31, half = lane >> 5;

    __shared__ __bf16 Pw[4][32][72];

    const __bf16* p0 = Opart + (size_t)g * 2048;
    const __bf16* p1 = Opart + ((size_t)2048 + g) * 2048;
#pragma unroll
    for (int rq = 0; rq < 8; ++rq) {
        bf16x4 a = *(const bf16x4*)(p0 + ((size_t)rq * 64 + lane) * 4);
        bf16x4 b = *(const bf16x4*)(p1 + ((size_t)rq * 64 + lane) * 4);
#pragma unroll
        for (int i = 0; i < 4; ++i) {
            int row = i + 8 * (rq & 3) + 4 * half;
            int n = nbase + row;
            float l = Lpart[(size_t)bh * 1024 + n] + Lpart[65536 + (size_t)bh * 1024 + n];
            float f = phase[(size_t)bh * 1024 + n] / l;
            Pw[wv][row][colq + 32 * (rq >> 2)] = (__bf16)(((float)a[i] + (float)b[i]) * f);
        }
    }
    // wave-private LDS RAW; compiler inserts the wait
    {
        int row = lane >> 1, dseg = lane & 1;
        int b_ = bh >> 3, hh = bh & 7;
        bf16x8 u0 = *(const bf16x8*)(&Pw[wv][row][dseg * 32]);
        bf16x8 u1 = *(const bf16x8*)(&Pw[wv][row][dseg * 32 + 8]);
        bf16x8 u2 = *(const bf16x8*)(&Pw[wv][row][dseg * 32 + 16]);
        bf16x8 u3 = *(const bf16x8*)(&Pw[wv][row][dseg * 32 + 24]);
        size_t obase = ((size_t)b_ * 1024 + nbase + row) * 512 + hh * 64 + dseg * 32;
        *(bf16x8*)(Ob + obase)      = u0;
        *(bf16x8*)(Ob + obase + 8)  = u1;
        *(bf16x8*)(Ob + obase + 16) = u2;
        *(bf16x8*)(Ob + obase + 24) = u3;
    }
}

// ---------------- output projection GEMM ----------------
__global__ __launch_bounds__(256) void gemm_out(const __bf16* __restrict__ X,
                                                const __bf16* __restrict__ W,
                                                const float* __restrict__ bo,
                                                float* __restrict__ out) {
    __shared__ __bf16 Xs[128][64];
    __shared__ __bf16 Ws[128][64];
    const int tid = threadIdx.x;
    const int wave = tid >> 6, lane = tid & 63;
    const int col = lane & 15, quad = lane >> 4;
    const int m_base = blockIdx.x * 128;
    const int j_base = blockIdx.y * 128;
    const int wm = (wave & 1) * 64;
    const int wn = (wave >> 1) * 64;
    const f32x4 fz = {0.f, 0.f, 0.f, 0.f};
    f32x4 acc[4][4];
#pragma unroll
    for (int i = 0; i < 4; ++i)
#pragma unroll
        for (int j = 0; j < 4; ++j) acc[i][j] = fz;

    for (int k0 = 0; k0 < 512; k0 += 64) {
#pragma unroll
        for (int p = 0; p < 4; ++p) {
            int s = tid + p * 256;
            int row = s >> 3, cc = (s & 7) * 8;
            GLOAD_LDS16(X + (size_t)(m_base + row) * 512 + k0 + cc, &Xs[0][0] + (size_t)s * 8);
            GLOAD_LDS16(W + (size_t)(j_base + row) * 512 + k0 + cc, &Ws[0][0] + (size_t)s * 8);
        }
        __syncthreads();
#pragma unroll
        for (int kk = 0; kk < 64; kk += 32) {
            bf16x8 xa[4], wb[4];
#pragma unroll
            for (int i = 0; i < 4; ++i) xa[i] = *(const bf16x8*)(&Xs[wm + i * 16 + col][kk + quad * 8]);
#pragma unroll
            for (int j = 0; j < 4; ++j) wb[j] = *(const bf16x8*)(&Ws[wn + j * 16 + col][kk + quad * 8]);
#pragma unroll
            for (int i = 0; i < 4; ++i)
#pragma unroll
                for (int j = 0; j < 4; ++j)
                    acc[i][j] = __builtin_amdgcn_mfma_f32_16x16x32_bf16(wb[i], xa[j], acc[i][j], 0, 0, 0);
        }
        __syncthreads();
    }
#pragma unroll
    for (int i = 0; i < 4; ++i) {
#pragma unroll
        for (int j = 0; j < 4; ++j) {
            int jabs = j_base + wn + i * 16 + quad * 4;
            int m = m_base + wm + j * 16 + col;
            f32x4 bv = *(const f32x4*)(bo + jabs);
            f32x4 o = acc[i][j] + bv;
            *(f32x4*)(out + (size_t)m * 512 + jabs) = o;
        }
    }
}

extern "C" void kernel_launch(void* const* d_in, const int* in_sizes, int n_in,
                              void* d_out, int out_size, void* d_ws, size_t ws_size,
                              hipStream_t stream) {
    (void)in_sizes; (void)n_in; (void)out_size; (void)ws_size;
    const float* x     = (const float*)d_in[0];
    const float* phase = (const float*)d_in[1];
    const float* E_rel = (const float*)d_in[2];
    const float* W_q   = (const float*)d_in[3];
    const float* W_k   = (const float*)d_in[4];
    const float* W_v   = (const float*)d_in[5];
    const float* W_o   = (const float*)d_in[6];
    const float* b_o   = (const float*)d_in[7];
    float* out = (float*)d_out;

    char* ws = (char*)d_ws;
    __bf16* xb    = (__bf16*)(ws);                 //  8,388,608 B
    __bf16* wqkv  = (__bf16*)(ws + 8388608);       //  1,572,864 B
    __bf16* wob   = (__bf16*)(ws + 9961472);       //    524,288 B
    __bf16* Ef    = (__bf16*)(ws + 10485760);      //    262,144 B fragment stream
    __bf16* Qb    = (__bf16*)(ws + 10747904);      //  8,388,608 B (pre-scaled)
    __bf16* Kf    = (__bf16*)(ws + 19136512);      //  8,388,608 B fragment stream
    __bf16* Vf    = (__bf16*)(ws + 27525120);      //  8,388,608 B fragment stream
    __bf16* Ob    = (__bf16*)(ws + 35913728);      //  8,388,608 B
    __bf16* Opart = (__bf16*)(ws + 44302336);      // 16,777,216 B partial O chunks
    float*  Lpart = (float*)(ws + 61079552);       //    524,288 B partial row-sums
                                                   // total 61,603,840 B

    cvt_all<<<dim3(5249), dim3(256), 0, stream>>>(x, E_rel, W_q, W_k, W_v, W_o,
                                                  xb, Ef, wqkv, wob);
    gemm_qkv<<<dim3(64, 12), dim3(256), 0, stream>>>(xb, wqkv, Qb, Kf, Vf);
    flash_kernel<<<dim3(2048), dim3(128), 0, stream>>>(Qb, Kf, Vf, Ef, Opart, Lpart);
    merge_kernel<<<dim3(512), dim3(256), 0, stream>>>(Opart, Lpart, phase, Ob);
    gemm_out<<<dim3(64, 4), dim3(256), 0, stream>>>(Ob, wob, b_o, out);
}

// Round 10
// 183.434 us; speedup vs baseline: 1.6325x; 1.3035x over previous
//
#include <hip/hip_runtime.h>

// PhaseMultiHeadAttention: B=8, N=1024, D=512, H=8, dh=64
// R10 = R5-exact flash shell (best measured: 81.5us) + E-tile carry
// (window advances 2 of 3 tiles/iter -> carry the shuffled 3rd tile:
// 12->8 QE MFMAs, 12->8 E loads, 48->32 bpermutes per iter) + prescaled Q
// + gemm_out 128x64 tiles (2 blocks/CU). No merge kernel.
// rel[n,m] = Q[n] . E_rel[m-n+N-1]

typedef __bf16 bf16x8 __attribute__((ext_vector_type(8)));
typedef __bf16 bf16x4 __attribute__((ext_vector_type(4)));
typedef float  f32x4  __attribute__((ext_vector_type(4)));
typedef float  f32x16 __attribute__((ext_vector_type(16)));

#if __has_builtin(__builtin_amdgcn_exp2f)
#define EXP2(x) __builtin_amdgcn_exp2f(x)
#else
#define EXP2(x) exp2f(x)
#endif

#define QSCALE 0.18033688011f   // (1/8) * log2(e), folded into Q at projection

// async global->LDS, 16B per lane; LDS dest = wave-uniform base + lane*16
#define GLOAD_LDS16(g, l)                                                      \
    __builtin_amdgcn_global_load_lds(                                          \
        (const __attribute__((address_space(1))) unsigned int*)(g),            \
        (__attribute__((address_space(3))) unsigned int*)(l), 16, 0, 0)

// Fragment-stream layouts (per bh, 65536 elems = 128KB):
//  Kf: [t32 = n>>5][ks = d>>4][lane = ((d>>3)&1)*32 + (n&31)][j = d&7]
//  Vf: [t64 = n>>6][ks = (n>>4)&3][dhalf = d>>5][lane = ((n>>3)&1)*32 + (d&31)][j = n&7]
//  Ef: like Kf over 2048 rows (l = row index): [t32 = l>>5][ks][lane][j]

// ---------------- fused fp32 -> bf16 conversion ----------------
__global__ __launch_bounds__(256) void cvt_all(const float* __restrict__ x,
                                               const float* __restrict__ E,
                                               const float* __restrict__ wq,
                                               const float* __restrict__ wk,
                                               const float* __restrict__ wv,
                                               const float* __restrict__ wo,
                                               __bf16* __restrict__ xb,
                                               __bf16* __restrict__ Ef,
                                               __bf16* __restrict__ wqkv,
                                               __bf16* __restrict__ wob) {
    int i = blockIdx.x * 256 + threadIdx.x;
    if (i >= 1081328 ? i < 1343472 : i < 1048576) {
        const float* s; __bf16* d; int off;
        if      (i < 1048576) { s = x;  d = xb;            off = i; }
        else if (i < 1146864) { s = wq; d = wqkv;          off = i - 1081328; }
        else if (i < 1212400) { s = wk; d = wqkv + 262144; off = i - 1146864; }
        else if (i < 1277936) { s = wv; d = wqkv + 524288; off = i - 1212400; }
        else                  { s = wo; d = wob;           off = i - 1277936; }
        float4 v = *(const float4*)(s + (size_t)off * 4);
        bf16x4 o;
        o[0] = (__bf16)v.x; o[1] = (__bf16)v.y; o[2] = (__bf16)v.z; o[3] = (__bf16)v.w;
        *(bf16x4*)(d + (size_t)off * 4) = o;
    } else if (i >= 1048576 && i < 1081328) {
        // E -> fragment stream
        int off = i - 1048576;
        float4 v = *(const float4*)(E + (size_t)off * 4);
        int e0i = off * 4;
        int l = e0i >> 6, d0 = e0i & 63;
        int t32 = l >> 5, cq = l & 31, ks = d0 >> 4, hf = (d0 >> 3) & 1, j = d0 & 7;
        bf16x4 o;
        o[0] = (__bf16)v.x; o[1] = (__bf16)v.y; o[2] = (__bf16)v.z; o[3] = (__bf16)v.w;
        *(bf16x4*)(Ef + ((size_t)((t32 * 4 + ks) * 64) + hf * 32 + cq) * 8 + j) = o;
    }
}

// ---------------- QKV projection GEMM ----------------
__global__ __launch_bounds__(256) void gemm_qkv(const __bf16* __restrict__ X,
                                                const __bf16* __restrict__ W,
                                                __bf16* __restrict__ Qb,
                                                __bf16* __restrict__ Kf,
                                                __bf16* __restrict__ Vf) {
    __shared__ __bf16 Xs[128][64];
    __shared__ __bf16 Ws[128][64];
    const int tid = threadIdx.x;
    const int wave = tid >> 6, lane = tid & 63;
    const int col = lane & 15, quad = lane >> 4;
    const int m_base = blockIdx.x * 128;
    const int j_base = blockIdx.y * 128;
    const bool qk = (j_base < 1024);
    const int wm = (wave & 1) * 64;
    const int wn = (wave >> 1) * 64;
    const f32x4 fz = {0.f, 0.f, 0.f, 0.f};
    f32x4 acc[4][4];
#pragma unroll
    for (int i = 0; i < 4; ++i)
#pragma unroll
        for (int j = 0; j < 4; ++j) acc[i][j] = fz;

    for (int k0 = 0; k0 < 512; k0 += 64) {
#pragma unroll
        for (int p = 0; p < 4; ++p) {
            int s = tid + p * 256;
            int row = s >> 3, cc = (s & 7) * 8;
            GLOAD_LDS16(X + (size_t)(m_base + row) * 512 + k0 + cc, &Xs[0][0] + (size_t)s * 8);
            GLOAD_LDS16(W + (size_t)(j_base + row) * 512 + k0 + cc, &Ws[0][0] + (size_t)s * 8);
        }
        __syncthreads();
#pragma unroll
        for (int kk = 0; kk < 64; kk += 32) {
            bf16x8 xa[4], wb[4];
#pragma unroll
            for (int i = 0; i < 4; ++i) xa[i] = *(const bf16x8*)(&Xs[wm + i * 16 + col][kk + quad * 8]);
#pragma unroll
            for (int j = 0; j < 4; ++j) wb[j] = *(const bf16x8*)(&Ws[wn + j * 16 + col][kk + quad * 8]);
            if (qk) {
#pragma unroll
                for (int i = 0; i < 4; ++i)
#pragma unroll
                    for (int j = 0; j < 4; ++j)
                        acc[i][j] = __builtin_amdgcn_mfma_f32_16x16x32_bf16(wb[i], xa[j], acc[i][j], 0, 0, 0);
            } else {
#pragma unroll
                for (int i = 0; i < 4; ++i)
#pragma unroll
                    for (int j = 0; j < 4; ++j)
                        acc[i][j] = __builtin_amdgcn_mfma_f32_16x16x32_bf16(xa[i], wb[j], acc[i][j], 0, 0, 0);
            }
        }
        __syncthreads();
    }
    if (qk) {
#pragma unroll
        for (int i = 0; i < 4; ++i) {
#pragma unroll
            for (int j = 0; j < 4; ++j) {
                int jabs = j_base + wn + i * 16 + quad * 4;
                int m = m_base + wm + j * 16 + col;
                int b_ = m >> 10, n = m & 1023;
                int rem = jabs & 511, h = rem >> 6, d = rem & 63;
                bf16x4 v;
                if (jabs < 512) {
                    v[0] = (__bf16)(acc[i][j][0] * QSCALE);
                    v[1] = (__bf16)(acc[i][j][1] * QSCALE);
                    v[2] = (__bf16)(acc[i][j][2] * QSCALE);
                    v[3] = (__bf16)(acc[i][j][3] * QSCALE);
                    *(bf16x4*)(Qb + (((size_t)b_ * 8 + h) * 1024 + n) * 64 + d) = v;
                } else {
                    v[0] = (__bf16)acc[i][j][0]; v[1] = (__bf16)acc[i][j][1];
                    v[2] = (__bf16)acc[i][j][2]; v[3] = (__bf16)acc[i][j][3];
                    int t32 = n >> 5, cq = n & 31, ks = d >> 4, hf = (d >> 3) & 1, jj = d & 7;
                    *(bf16x4*)(Kf + (size_t)(b_ * 8 + h) * 65536 +
                               ((size_t)((t32 * 4 + ks) * 64) + hf * 32 + cq) * 8 + jj) = v;
                }
            }
        }
    } else {
#pragma unroll
        for (int i = 0; i < 4; ++i) {
#pragma unroll
            for (int j = 0; j < 4; ++j) {
                int m = m_base + wm + i * 16 + quad * 4;
                int b_ = m >> 10, n = m & 1023;
                int jabs = j_base + wn + j * 16 + col;
                int rem = jabs & 511, h = rem >> 6, d = rem & 63;
                int t64 = n >> 6, ks = (n >> 4) & 3, hf = (n >> 3) & 1, jj = n & 7;
                int dhalf = d >> 5, cq = d & 31;
                bf16x4 v;
                v[0] = (__bf16)acc[i][j][0]; v[1] = (__bf16)acc[i][j][1];
                v[2] = (__bf16)acc[i][j][2]; v[3] = (__bf16)acc[i][j][3];
                *(bf16x4*)(Vf + (size_t)(b_ * 8 + h) * 65536 +
                           ((size_t)(((t64 * 4 + ks) * 2 + dhalf) * 64) + hf * 32 + cq) * 8 + jj) = v;
            }
        }
    }
}

// ---------------- flash attention (R5 shell + E-tile carry) ----------------
// grid: x = 16 (64-row n-tiles), y = 64 (b*h). 128 threads = 2 waves, 32 rows each.
__global__ __launch_bounds__(128) void flash_kernel(const __bf16* __restrict__ Qb,
                                                    const __bf16* __restrict__ Kf,
                                                    const __bf16* __restrict__ Vf,
                                                    const __bf16* __restrict__ Ef,
                                                    const float* __restrict__ phase,
                                                    __bf16* __restrict__ Ob) {
    const int bh = blockIdx.y;
    const int n0 = blockIdx.x * 64;
    const int w = threadIdx.x >> 6, lane = threadIdx.x & 63;
    const int colq = lane & 31, half = lane >> 5;
    const int nbase = n0 + w * 32;

    __shared__ __bf16 Pw[2][32][72];   // per-wave P staging; conflict-free

    f32x16 z16;
#pragma unroll
    for (int i = 0; i < 16; ++i) z16[i] = 0.f;

    bf16x8 a_q[4];
#pragma unroll
    for (int ks = 0; ks < 4; ++ks)
        a_q[ks] = *(const bf16x8*)(Qb + ((size_t)bh * 1024 + nbase + colq) * 64 + ks * 16 + half * 8);

    f32x16 o0 = z16, o1 = z16;
    float rowsum[16];
#pragma unroll
    for (int i = 0; i < 16; ++i) rowsum[i] = 0.f;

    const __bf16* Kfb = Kf + (size_t)bh * 65536;
    const __bf16* Vfb = Vf + (size_t)bh * 65536;

    const int te0 = (992 - nbase) >> 5;   // first window tile (>= 0)

    // prologue: shuffled values of tile te0 (the carried "A" tile)
    float shA[16];
    {
        f32x16 qeA = z16;
#pragma unroll
        for (int ks = 0; ks < 4; ++ks) {
            bf16x8 e = *(const bf16x8*)(Ef + ((size_t)((te0 * 4 + ks) * 64) + lane) * 8);
            qeA = __builtin_amdgcn_mfma_f32_32x32x16_bf16(a_q[ks], e, qeA, 0, 0, 0);
        }
#pragma unroll
        for (int r = 0; r < 16; ++r) {
            int row = (r & 3) + 8 * (r >> 2) + 4 * half;
            int tt = colq + 31 - row;
            int src = (tt & 31) | (half << 5);
            shA[r] = __shfl(qeA[r], src, 64);
        }
    }

#pragma unroll 1
    for (int t = 0; t < 16; ++t) {
        const int m0 = t * 64;
        const int t32 = m0 >> 5;
        const int teB = te0 + 2 * t + 1;   // two new window tiles this iter
        f32x16 qeB = z16, qeC = z16, s0 = z16, s1 = z16;
#pragma unroll
        for (int ks = 0; ks < 4; ++ks) {
            bf16x8 e1 = *(const bf16x8*)(Ef + ((size_t)((teB * 4 + ks) * 64) + lane) * 8);
            bf16x8 e2 = *(const bf16x8*)(Ef + ((size_t)(((teB + 1) * 4 + ks) * 64) + lane) * 8);
            bf16x8 k0 = *(const bf16x8*)(Kfb + ((size_t)((t32 * 4 + ks) * 64) + lane) * 8);
            bf16x8 k1 = *(const bf16x8*)(Kfb + ((size_t)(((t32 + 1) * 4 + ks) * 64) + lane) * 8);
            qeB = __builtin_amdgcn_mfma_f32_32x32x16_bf16(a_q[ks], e1, qeB, 0, 0, 0);
            qeC = __builtin_amdgcn_mfma_f32_32x32x16_bf16(a_q[ks], e2, qeC, 0, 0, 0);
            s0  = __builtin_amdgcn_mfma_f32_32x32x16_bf16(a_q[ks], k0, s0, 0, 0, 0);
            s1  = __builtin_amdgcn_mfma_f32_32x32x16_bf16(a_q[ks], k1, s1, 0, 0, 0);
        }
        // skew: shuffle only the 2 new tiles; carry shA from previous iter
#pragma unroll
        for (int r = 0; r < 16; ++r) {
            int row = (r & 3) + 8 * (r >> 2) + 4 * half;
            int tt = colq + 31 - row;              // 0..62
            int src = (tt & 31) | (half << 5);
            float shB = __shfl(qeB[r], src, 64);
            float shC = __shfl(qeC[r], src, 64);
            bool sel = (tt >= 32);
            float rel0 = sel ? shB : shA[r];
            float rel1 = sel ? shC : shB;
            float p0 = EXP2(s0[r] + rel0);         // Q pre-scaled
            float p1 = EXP2(s1[r] + rel1);
            rowsum[r] += p0 + p1;
            Pw[w][row][colq]      = (__bf16)p0;
            Pw[w][row][32 + colq] = (__bf16)p1;
            shA[r] = shC;                          // carry for next iter
        }
        asm volatile("s_waitcnt lgkmcnt(0)" ::: "memory");
        // O += P @ V  (A-frag from Pw, B-frag = Vf fragment stream)
#pragma unroll
        for (int ks = 0; ks < 4; ++ks) {
            bf16x8 pa = *(const bf16x8*)(&Pw[w][colq][ks * 16 + half * 8]);
            bf16x8 v0 = *(const bf16x8*)(Vfb + ((size_t)(((t * 4 + ks) * 2 + 0) * 64) + lane) * 8);
            bf16x8 v1 = *(const bf16x8*)(Vfb + ((size_t)(((t * 4 + ks) * 2 + 1) * 64) + lane) * 8);
            o0 = __builtin_amdgcn_mfma_f32_32x32x16_bf16(pa, v0, o0, 0, 0, 0);
            o1 = __builtin_amdgcn_mfma_f32_32x32x16_bf16(pa, v1, o1, 0, 0, 0);
        }
        asm volatile("" ::: "memory");
    }

    // epilogue: l reduce, scale by phase/l, store via Pw for coalescing
    const int b_ = bh >> 3, hh = bh & 7;
#pragma unroll
    for (int r = 0; r < 16; ++r) {
        float l = rowsum[r];
        l += __shfl_xor(l, 1, 32);
        l += __shfl_xor(l, 2, 32);
        l += __shfl_xor(l, 4, 32);
        l += __shfl_xor(l, 8, 32);
        l += __shfl_xor(l, 16, 32);
        int row = (r & 3) + 8 * (r >> 2) + 4 * half;
        float f = phase[(size_t)bh * 1024 + nbase + row] / l;
        Pw[w][row][colq]      = (__bf16)(o0[r] * f);
        Pw[w][row][32 + colq] = (__bf16)(o1[r] * f);
    }
    asm volatile("s_waitcnt lgkmcnt(0)" ::: "memory");
    {
        int row = lane >> 1, dseg = lane & 1;
        bf16x8 u0 = *(const bf16x8*)(&Pw[w][row][dseg * 32]);
        bf16x8 u1 = *(const bf16x8*)(&Pw[w][row][dseg * 32 + 8]);
        bf16x8 u2 = *(const bf16x8*)(&Pw[w][row][dseg * 32 + 16]);
        bf16x8 u3 = *(const bf16x8*)(&Pw[w][row][dseg * 32 + 24]);
        size_t obase = ((size_t)b_ * 1024 + nbase + row) * 512 + hh * 64 + dseg * 32;
        *(bf16x8*)(Ob + obase)      = u0;
        *(bf16x8*)(Ob + obase + 8)  = u1;
        *(bf16x8*)(Ob + obase + 16) = u2;
        *(bf16x8*)(Ob + obase + 24) = u3;
    }
}

// ---------------- output projection GEMM (128x64 tiles, 2 blocks/CU) ----------------
__global__ __launch_bounds__(256) void gemm_out(const __bf16* __restrict__ X,
                                                const __bf16* __restrict__ W,
                                                const float* __restrict__ bo,
                                                float* __restrict__ out) {
    __shared__ __bf16 Xs[128][64];
    __shared__ __bf16 Ws[64][64];
    const int tid = threadIdx.x;
    const int wave = tid >> 6, lane = tid & 63;
    const int col = lane & 15, quad = lane >> 4;
    const int m_base = blockIdx.x * 128;
    const int j_base = blockIdx.y * 64;
    const int wm = (wave & 1) * 64;
    const int wn = (wave >> 1) * 32;
    const f32x4 fz = {0.f, 0.f, 0.f, 0.f};
    f32x4 acc[2][4];
#pragma unroll
    for (int i = 0; i < 2; ++i)
#pragma unroll
        for (int j = 0; j < 4; ++j) acc[i][j] = fz;

    for (int k0 = 0; k0 < 512; k0 += 64) {
#pragma unroll
        for (int p = 0; p < 4; ++p) {
            int s = tid + p * 256;
            int row = s >> 3, cc = (s & 7) * 8;
            GLOAD_LDS16(X + (size_t)(m_base + row) * 512 + k0 + cc, &Xs[0][0] + (size_t)s * 8);
        }
#pragma unroll
        for (int p = 0; p < 2; ++p) {
            int s = tid + p * 256;
            int row = s >> 3, cc = (s & 7) * 8;
            GLOAD_LDS16(W + (size_t)(j_base + row) * 512 + k0 + cc, &Ws[0][0] + (size_t)s * 8);
        }
        __syncthreads();
#pragma unroll
        for (int kk = 0; kk < 64; kk += 32) {
            bf16x8 xa[4], wb[2];
#pragma unroll
            for (int j = 0; j < 4; ++j) xa[j] = *(const bf16x8*)(&Xs[wm + j * 16 + col][kk + quad * 8]);
#pragma unroll
            for (int i = 0; i < 2; ++i) wb[i] = *(const bf16x8*)(&Ws[wn + i * 16 + col][kk + quad * 8]);
#pragma unroll
            for (int i = 0; i < 2; ++i)
#pragma unroll
                for (int j = 0; j < 4; ++j)
                    acc[i][j] = __builtin_amdgcn_mfma_f32_16x16x32_bf16(wb[i], xa[j], acc[i][j], 0, 0, 0);
        }
        __syncthreads();
    }
#pragma unroll
    for (int i = 0; i < 2; ++i) {
#pragma unroll
        for (int j = 0; j < 4; ++j) {
            int jabs = j_base + wn + i * 16 + quad * 4;
            int m = m_base + wm + j * 16 + col;
            f32x4 bv = *(const f32x4*)(bo + jabs);
            f32x4 o = acc[i][j] + bv;
            *(f32x4*)(out + (size_t)m * 512 + jabs) = o;
        }
    }
}

extern "C" void kernel_launch(void* const* d_in, const int* in_sizes, int n_in,
                              void* d_out, int out_size, void* d_ws, size_t ws_size,
                              hipStream_t stream) {
    (void)in_sizes; (void)n_in; (void)out_size; (void)ws_size;
    const float* x     = (const float*)d_in[0];
    const float* phase = (const float*)d_in[1];
    const float* E_rel = (const float*)d_in[2];
    const float* W_q   = (const float*)d_in[3];
    const float* W_k   = (const float*)d_in[4];
    const float* W_v   = (const float*)d_in[5];
    const float* W_o   = (const float*)d_in[6];
    const float* b_o   = (const float*)d_in[7];
    float* out = (float*)d_out;

    char* ws = (char*)d_ws;
    __bf16* xb   = (__bf16*)(ws);                 //  8,388,608 B
    __bf16* wqkv = (__bf16*)(ws + 8388608);       //  1,572,864 B
    __bf16* wob  = (__bf16*)(ws + 9961472);       //    524,288 B
    __bf16* Ef   = (__bf16*)(ws + 10485760);      //    262,144 B fragment stream
    __bf16* Qb   = (__bf16*)(ws + 10747904);      //  8,388,608 B (pre-scaled)
    __bf16* Kf   = (__bf16*)(ws + 19136512);      //  8,388,608 B fragment stream
    __bf16* Vf   = (__bf16*)(ws + 27525120);      //  8,388,608 B fragment stream
    __bf16* Ob   = (__bf16*)(ws + 35913728);      //  8,388,608 B

    cvt_all<<<dim3(5249), dim3(256), 0, stream>>>(x, E_rel, W_q, W_k, W_v, W_o,
                                                  xb, Ef, wqkv, wob);
    gemm_qkv<<<dim3(64, 12), dim3(256), 0, stream>>>(xb, wqkv, Qb, Kf, Vf);
    flash_kernel<<<dim3(16, 64), dim3(128), 0, stream>>>(Qb, Kf, Vf, Ef, phase, Ob);
    gemm_out<<<dim3(64, 8), dim3(256), 0, stream>>>(Ob, wob, b_o, out);
}